// Round 1
// baseline (2780.300 us; speedup 1.0000x reference)
//
#include <hip/hip_runtime.h>

// DistributionTracker: per-label scatter-add of [count | sum(X) | sum(X^2)]
// X: (N, 128) fp32, labels: (N,) int32, out: (classes, 257) fp32 row-major.
//
// Strategy: class-group LDS privatization.
//   - classes split into groups of CG=63 (63*257*4B = 63.2 KiB LDS/block)
//   - grid = (row_chunks, n_groups); each block scans its chunk's labels,
//     processes only rows whose label falls in its class group
//   - wave-cooperative: 64 labels loaded coalesced, __ballot picks in-group
//     rows, whole wave gathers the 512B row and does LDS float adds
//   - epilogue: LDS partials -> global via hardware f32 atomics (skip zeros)

constexpr int THREADS = 512;           // 8 waves/block
constexpr int WAVES   = THREADS / 64;
constexpr int DIM     = 128;
constexpr int ROWLEN  = 2 * DIM + 1;   // 257: [num | miu(128) | sqr(128)]
constexpr int CG      = 63;            // classes per group (63*257*4 = 64764 B LDS)

__global__ __launch_bounds__(THREADS, 2)
void dist_tracker_kernel(const float* __restrict__ X,
                         const int*   __restrict__ labels,
                         float*       __restrict__ out,
                         int N, int classes, int rows_per_chunk)
{
    __shared__ float part[CG * ROWLEN];

    const int tid   = threadIdx.x;
    const int lane  = tid & 63;
    const int wid   = tid >> 6;
    const int gbase = blockIdx.y * CG;

    // zero the LDS partial histogram
    for (int i = tid; i < CG * ROWLEN; i += THREADS) part[i] = 0.0f;
    __syncthreads();

    const long long row0 = (long long)blockIdx.x * rows_per_chunk;
    int rows = rows_per_chunk;
    if (row0 + rows > N) rows = (int)((long long)N - row0);

    // each wave scans 64-row batches of this chunk
    for (int base = wid * 64; base < rows; base += WAVES * 64) {
        const int nb = min(64, rows - base);
        int lab = -1;
        if (lane < nb) lab = labels[row0 + base + lane];
        const int  lc = lab - gbase;
        const bool in = (lab >= 0) && (lc >= 0) && (lc < CG) && (lab < classes);
        unsigned long long mask = __ballot(in);

        while (mask) {
            const int j = __ffsll((long long)mask) - 1;
            mask &= mask - 1;
            const int c = __shfl(lc, j);                 // wave-uniform class
            const size_t ridx = (size_t)(row0 + base + j) * DIM;
            const float x0 = X[ridx + lane];             // d = lane
            const float x1 = X[ridx + lane + 64];        // d = lane + 64
            float* p = &part[c * ROWLEN];
            atomicAdd(&p[1   + lane], x0);               // miu, d 0..63
            atomicAdd(&p[65  + lane], x1);               // miu, d 64..127
            atomicAdd(&p[129 + lane], x0 * x0);          // sqr, d 0..63
            atomicAdd(&p[193 + lane], x1 * x1);          // sqr, d 64..127
            if (lane == 0) atomicAdd(&p[0], 1.0f);       // count
        }
    }
    __syncthreads();

    // flush partials to global (skip exact zeros: adding 0 is a no-op)
    const int cmax  = min(CG, classes - gbase);
    const int total = cmax * ROWLEN;
    float* gout = out + (size_t)gbase * ROWLEN;
    for (int i = tid; i < total; i += THREADS) {
        const float v = part[i];
        if (v != 0.0f) unsafeAtomicAdd(&gout[i], v);
    }
}

extern "C" void kernel_launch(void* const* d_in, const int* in_sizes, int n_in,
                              void* d_out, int out_size, void* d_ws, size_t ws_size,
                              hipStream_t stream)
{
    const float* X      = (const float*)d_in[0];
    const int*   labels = (const int*)d_in[1];
    float*       out    = (float*)d_out;

    const int N       = in_sizes[1];                 // labels element count
    const int classes = out_size / ROWLEN;           // (classes, 257) output

    // accumulate-into-output: start from zeros every call (harness poisons)
    hipMemsetAsync(d_out, 0, (size_t)out_size * sizeof(float), stream);

    const int target_chunks = 32;
    int rpc = (N + target_chunks - 1) / target_chunks;
    const int batch = WAVES * 64;                    // rows per block pass
    rpc = ((rpc + batch - 1) / batch) * batch;
    const int chunks = (N + rpc - 1) / rpc;
    const int groups = (classes + CG - 1) / CG;

    dim3 grid(chunks, groups);
    dist_tracker_kernel<<<grid, THREADS, 0, stream>>>(X, labels, out,
                                                      N, classes, rpc);
}